// Round 3
// baseline (185.120 us; speedup 1.0000x reference)
//
#include <hip/hip_runtime.h>

#define N_ELEM 4096
#define BLOCK 256
#define PER 16             // elems per thread
#define NG (PER / 2)       // v2f groups per thread
#define NWAVE (BLOCK / 64)
#define NITER 40           // hard cap (safety); expect exit at ~10-16
#define CAPACITY 600.0f
#define DAMPING 1e-3f
// mu = 4^-it for it<5 (1, .25, .0625, .0156, .0039), then 1e-3. The mu=1e-3
// barrier problem is strictly convex => unique minimizer => output is
// path-independent; the exit gate (below) only fires once an UNCLAMPED,
// tiny Newton step has occurred at the final mu, certifying convergence.
#define MU_FINAL_IT 5
// R12: R11 post-mortem proved the old gates NEVER fired (bit-identical
// output across R9/R10/R11; time == NITER*per-iter-cost): the global
// min-alpha fraction-to-boundary makes one near-bound element throttle all
// 4096 -> ~40 crawling iterations. Fix: per-element clamp (truncated
// Newton): x+ = med3(x - dxn, 0.01x, 0.99+0.01x). No block-uniform alpha
// => ONE reduce/barrier per iter; F2 recomputed exactly as w.x - cap.
// Exit gate: prev step unclamped everywhere AND max|dx| < ABS_EPS => we
// are in the pure-Newton quadratic basin at final mu; the current phaseA +
// dlam then doubles as the final KKT refine (out = x - (g + dlam*wih)).
#define ABS_EPS 2e-3f

typedef float v2f __attribute__((ext_vector_type(2)));
union F4V2 { float4 f4; v2f v[2]; };

__device__ __forceinline__ float raw_rcp(float a) { return __builtin_amdgcn_rcpf(a); }
__device__ __forceinline__ v2f pk_rcp(v2f a) {
    v2f r; r.x = raw_rcp(a.x); r.y = raw_rcp(a.y); return r;
}
__device__ __forceinline__ v2f pk_max(v2f a, v2f b) { return __builtin_elementwise_max(a, b); }
__device__ __forceinline__ v2f pk_min(v2f a, v2f b) { return __builtin_elementwise_min(a, b); }
__device__ __forceinline__ v2f pk_abs(v2f a) { return __builtin_elementwise_abs(a); }

__device__ __forceinline__ float bcast_first(float v) {
    return __uint_as_float(__builtin_amdgcn_readfirstlane(__float_as_uint(v)));
}

// Init-only fused 2-value block sum-reduction (ws). ONE barrier.
__device__ __forceinline__ void block_reduce2(float& a, float& b, float* buf) {
    #pragma unroll
    for (int off = 32; off > 0; off >>= 1) {
        a += __shfl_xor(a, off, 64);
        b += __shfl_xor(b, off, 64);
    }
    const int wave = threadIdx.x >> 6;
    if ((threadIdx.x & 63) == 0) { buf[2 * wave] = a; buf[2 * wave + 1] = b; }
    __syncthreads();
    float a0 = 0.0f, b0 = 0.0f;
    #pragma unroll
    for (int i = 0; i < NWAVE; ++i) { a0 += buf[2 * i]; b0 += buf[2 * i + 1]; }
    a = a0; b = b0;
}

// R12: THE per-iteration reduce — 3 sums (w.x, s1, s2) + 1 max (exit gate),
// one butterfly, one float4 LDS slot per wave, ONE barrier. buf[0..3]
// stage-2 reads are wave-broadcast (conflict-free).
__device__ __forceinline__ void block_reduce4(float& a, float& b, float& c,
                                              float& m, float4* buf) {
    #pragma unroll
    for (int off = 32; off > 0; off >>= 1) {
        a += __shfl_xor(a, off, 64);
        b += __shfl_xor(b, off, 64);
        c += __shfl_xor(c, off, 64);
        m = fmaxf(m, __shfl_xor(m, off, 64));
    }
    const int wave = threadIdx.x >> 6;
    if ((threadIdx.x & 63) == 0) { float4 p = {a, b, c, m}; buf[wave] = p; }
    __syncthreads();
    float4 p = buf[0];
    #pragma unroll
    for (int i = 1; i < NWAVE; ++i) {
        float4 q = buf[i];
        p.x += q.x; p.y += q.y; p.z += q.z; p.w = fmaxf(p.w, q.w);
    }
    a = p.x; b = p.y; c = p.z; m = p.w;
}

// Layout (R6/R7): c,w in LDS (32KB, ds_read_b128); x,g,wih in regs (tinv
// dropped — no fraction-to-boundary ratios anymore). R10 lesson: VALU-issue
// bound at ~65% busy ceiling, occupancy NOT the lever; time = inst/iter ×
// iters. R12 attacks iters (40 -> ~12) and barriers/iter (2 -> 1).
__global__ __launch_bounds__(BLOCK, 4) void ipm_knapsack_kernel(
        const float* __restrict__ costs,
        const float* __restrict__ weights,
        float* __restrict__ out) {
    __shared__ float4 c4s[N_ELEM / 4];    // 16 KB: -costs (this row)
    __shared__ float4 w4s[N_ELEM / 4];    // 16 KB: weights
    __shared__ float4 ldsR[2][NWAVE];     // parity-buffered reduce4 scratch
    __shared__ float  ldsF[2 * NWAVE];    // init reduce
    const int row = blockIdx.x;
    const int t   = threadIdx.x;

    v2f x[NG], g[NG], wih[NG];

    // ---- Stage c (negated) and w into LDS; accumulate sum(w) ----
    const float4* cg = reinterpret_cast<const float4*>(costs + (size_t)row * N_ELEM);
    const float4* wg = reinterpret_cast<const float4*>(weights);
    float ws = 0.0f, zz = 0.0f;
    #pragma unroll
    for (int j = 0; j < NG / 2; ++j) {
        float4 cc = cg[t + BLOCK * j];
        float4 ww = wg[t + BLOCK * j];
        cc.x = -cc.x; cc.y = -cc.y; cc.z = -cc.z; cc.w = -cc.w;
        c4s[t + BLOCK * j] = cc;
        w4s[t + BLOCK * j] = ww;
        ws += (ww.x + ww.y) + (ww.z + ww.w);
    }
    block_reduce2(ws, zz, ldsF);      // barrier also orders LDS staging

    const float x0 = CAPACITY / ws;
    #pragma unroll
    for (int k = 0; k < NG; ++k) { v2f x0v = {x0, x0}; x[k] = x0v; }
    float lam = 0.0f;
    float gate_t = 1e9f;              // lagged per-thread gate (big: no early exit)

    // Packed phase A: u=x(1-x); one rcp -> 1/u and 1/H=u^3*r. Also
    // accumulates s0 = sum(w*x) so F2 = s0 - cap is exact every iteration.
    auto phaseA = [&](float mu, float& s0, float& s1, float& s2) {
        const float m2mu = -2.0f * mu;
        v2f s0v = {0.0f, 0.0f}, s1v = {0.0f, 0.0f}, s2v = {0.0f, 0.0f};
        #pragma unroll
        for (int j = 0; j < NG / 2; ++j) {
            F4V2 cv, wv;
            cv.f4 = c4s[t + BLOCK * j];
            wv.f4 = w4s[t + BLOCK * j];
            #pragma unroll
            for (int h = 0; h < 2; ++h) {
                const int k = 2 * j + h;
                const v2f xk = x[k], wk = wv.v[h];
                const v2f p  = 1.0f - xk;
                const v2f u  = xk * p;
                const v2f d  = m2mu * u + mu;         // mu*(1-2u) > 0
                const v2f r  = pk_rcp(u * d);
                const v2f ti = r * d;                 // 1/u
                const v2f q  = xk - p;                // 2x-1
                const v2f f1 = (mu * ti) * q + (lam * wk + cv.v[h]);
                const v2f u2 = u * u;
                const v2f iH = (u2 * u) * r;          // 1/H
                const v2f gk = f1 * iH;
                const v2f wi = wk * iH;
                s0v = wk * xk + s0v;
                s1v = wk * gk + s1v;
                s2v = wk * wi + s2v;
                g[k] = gk; wih[k] = wi;
            }
        }
        s0 = s0v.x + s0v.y; s1 = s1v.x + s1v.y; s2 = s2v.x + s2v.y;
    };

    // Epilogue: out = x - (g + dlam*wih) — the KKT refine step (unclamped).
    auto emit = [&](float dlam) {
        float4* o4 = reinterpret_cast<float4*>(out + (size_t)row * N_ELEM);
        #pragma unroll
        for (int j = 0; j < NG / 2; ++j) {
            F4V2 ov;
            #pragma unroll
            for (int h = 0; h < 2; ++h) {
                const int k = 2 * j + h;
                const v2f dxn = dlam * wih[k] + g[k];
                ov.v[h] = x[k] - dxn;
            }
            o4[t + BLOCK * j] = ov.f4;
        }
    };

    for (int it = 0; it < NITER; ++it) {
        // mu = 4^-it for it<5, else DAMPING (exact via exponent bits).
        const float mu = (it < MU_FINAL_IT)
                       ? __uint_as_float((unsigned)(127 - 2 * it) << 23) : DAMPING;
        float s0, s1, s2;
        phaseA(mu, s0, s1, s2);
        float gmax = gate_t;
        block_reduce4(s0, s1, s2, gmax, ldsR[it & 1]);    // ONE barrier/iter
        const float f2   = s0 - CAPACITY;                  // exact F2 = w.x - cap
        const float dlam = bcast_first((f2 - s1) * raw_rcp(s2));

        // Exit: previous step (at it-1 >= MU_FINAL_IT, i.e. mu final) was
        // fully unclamped with max|dx| < eps => quadratic basin; this
        // iteration's phaseA + dlam IS the final refine. Uniform branch.
        if (it > MU_FINAL_IT && bcast_first(gmax) < ABS_EPS) { emit(dlam); return; }

        // ---- Phase B: per-element truncated Newton step (no divides) ----
        // dxn = -dx. Target clamp keeps each element within 99% of its own
        // distance to {0,1}: x+ = min(max(x - dxn, 0.01x), 0.99 + 0.01x).
        v2f ga = {0.0f, 0.0f};
        #pragma unroll
        for (int k = 0; k < NG; ++k) {
            const v2f dxn  = dlam * wih[k] + g[k];
            const v2f xk   = x[k];
            const v2f cand = xk - dxn;
            const v2f lo   = 0.01f * xk;
            const v2f hi   = lo + 0.99f;
            const v2f xn   = pk_min(pk_max(cand, lo), hi);
            x[k] = xn;
            const v2f diff = cand - xn;               // nonzero iff clamped
            ga = pk_max(ga, pk_max(pk_abs(dxn), pk_abs(diff)));
        }
        gate_t = fmaxf(ga.x, ga.y);
        lam += dlam;
    }

    // Cap reached without certified convergence: one last refine at DAMPING.
    float s0, s1, s2;
    phaseA(DAMPING, s0, s1, s2);
    float dummy = 0.0f;
    block_reduce4(s0, s1, s2, dummy, ldsR[NITER & 1]);
    emit(bcast_first((s0 - CAPACITY - s1) * raw_rcp(s2)));
}

extern "C" void kernel_launch(void* const* d_in, const int* in_sizes, int n_in,
                              void* d_out, int out_size, void* d_ws, size_t ws_size,
                              hipStream_t stream) {
    const float* costs   = (const float*)d_in[0];
    const float* weights = (const float*)d_in[1];
    float* out = (float*)d_out;
    const int B = in_sizes[0] / N_ELEM;   // 2048 rows
    ipm_knapsack_kernel<<<B, BLOCK, 0, stream>>>(costs, weights, out);
}

// Round 4
// 120.260 us; speedup vs baseline: 1.5393x; 1.5393x over previous
//
#include <hip/hip_runtime.h>

#define N_ELEM 4096
#define BLOCK 256
#define PER 16             // elems per thread
#define NG (PER / 2)       // v2f groups per thread = 8
#define NWAVE (BLOCK / 64) // 4
#define CAPACITY 600.0f
#define DAMPING 1e-3f
// R13: exact per-element coordinate solve (quadratic formula) + scalar
// Newton on lam. x(lam) = root in (0,1) of  r x^2 - (r+2mu) x + mu = 0,
// r = c + lam*w; discriminant D = r^2 + 4mu^2 EXACTLY (no cancellation).
// Stable: x' = 2mu/(|r| + 2mu + sqrt(D)), x = 0.5 - copysign(0.5 - x', r).
// F1 == 0 by construction => s1 == 0 => dlam = (w.x - cap)/sum(w^2/H), and
// w/H = mu*w/(A^2+B^2) with A = mu/x' = den/2, B = A - |r| (H symmetric
// under x<->1-x). Emit out = x - dlam*w/H == reference _kkt_refine at F1=0.
// Only loop-carried state: scalar lam. Schedule: 3 Newtons at mu=1 (settle
// lam from 0), x(1/4) ladder to 1e-3, final-mu Newtons (quadratic), scalar
// gate |dlam| < GATE_EPS after >=2 final-mu iters. Worst case NITER=17
// deterministic. R12 post-mortem: absmax 0.0039 is the intrinsic gap
// between the converged mu=1e-3 minimizer and the reference's 40-iter
// path; per-element max|dx| gates never settle (transients), scalar |dlam|
// does.
#define NITER 17
#define N_MU1 3            // iterations at mu=1 from lam=0
#define FIRST_FINAL 7      // first it with mu = DAMPING
#define GATE_IT 9          // earliest exit (>=2 final-mu Newtons done)
#define GATE_EPS 1e-5f     // |dlam| gate: x-error <= w*iH*|dlam| ~ 6e-4

typedef float v2f __attribute__((ext_vector_type(2)));
union F4V2 { float4 f4; v2f v[2]; };

__device__ __forceinline__ float raw_rcp(float a)  { return __builtin_amdgcn_rcpf(a); }
__device__ __forceinline__ float raw_sqrt(float a) { return __builtin_amdgcn_sqrtf(a); }
__device__ __forceinline__ v2f pk_rcp(v2f a) {
    v2f r; r.x = raw_rcp(a.x); r.y = raw_rcp(a.y); return r;
}
__device__ __forceinline__ v2f pk_sqrt(v2f a) {
    v2f r; r.x = raw_sqrt(a.x); r.y = raw_sqrt(a.y); return r;
}
__device__ __forceinline__ v2f pk_copysign(v2f m, v2f s) {
    v2f r; r.x = __builtin_copysignf(m.x, s.x); r.y = __builtin_copysignf(m.y, s.y);
    return r;
}
__device__ __forceinline__ float bcast_first(float v) {
    return __uint_as_float(__builtin_amdgcn_readfirstlane(__float_as_uint(v)));
}

// Fused 2-value block sum-reduction; ONE barrier; result uniform on all
// threads. Stage 2: b64 read of buf[lane&3] (broadcast within 16-lane
// groups, conflict-free) + 2-level xor-shfl.
__device__ __forceinline__ void block_reduce2(float& a, float& b, v2f* buf) {
    #pragma unroll
    for (int off = 32; off > 0; off >>= 1) {
        a += __shfl_xor(a, off, 64);
        b += __shfl_xor(b, off, 64);
    }
    const int wave = threadIdx.x >> 6;
    if ((threadIdx.x & 63) == 0) { v2f p = {a, b}; buf[wave] = p; }
    __syncthreads();
    v2f p = buf[threadIdx.x & (NWAVE - 1)];
    #pragma unroll
    for (int off = 1; off < NWAVE; off <<= 1) {
        p.x += __shfl_xor(p.x, off, 64);
        p.y += __shfl_xor(p.y, off, 64);
    }
    a = p.x; b = p.y;
}

// R13 layout: c,w,x,wih ALL in registers (~64 data VGPR) — no 32KB LDS
// tile, no per-iter ds_reads, one barrier/iter (the reduce). LDS = 32 B of
// reduce scratch. Per iter: pure-VALU element pass (fma/mul + 1 sqrt +
// 2 rcp per elem) + reduce2 + scalar lam update.
__global__ __launch_bounds__(BLOCK, 4) void ipm_knapsack_kernel(
        const float* __restrict__ costs,
        const float* __restrict__ weights,
        float* __restrict__ out) {
    __shared__ v2f ldsR[2][NWAVE];        // parity-buffered reduce scratch
    const int row = blockIdx.x;
    const int t   = threadIdx.x;

    v2f c[NG], w[NG], x[NG], wih[NG];

    // ---- Load c (negated) and w into registers ----
    const float4* cg = reinterpret_cast<const float4*>(costs + (size_t)row * N_ELEM);
    const float4* wg = reinterpret_cast<const float4*>(weights);
    #pragma unroll
    for (int j = 0; j < NG / 2; ++j) {
        F4V2 cc, ww;
        cc.f4 = cg[t + BLOCK * j];
        ww.f4 = wg[t + BLOCK * j];
        cc.f4.x = -cc.f4.x; cc.f4.y = -cc.f4.y; cc.f4.z = -cc.f4.z; cc.f4.w = -cc.f4.w;
        c[2 * j] = cc.v[0]; c[2 * j + 1] = cc.v[1];
        w[2 * j] = ww.v[0]; w[2 * j + 1] = ww.v[1];
    }

    float lam = 0.0f, dlam = 0.0f;

    for (int it = 0; it < NITER; ++it) {
        // mu: 1,1,1, .25, .0625, .015625, .00390625, then DAMPING forever.
        const float mu = (it < N_MU1) ? 1.0f
                       : (it < FIRST_FINAL)
                         ? __uint_as_float((unsigned)(127 - 2 * (it - (N_MU1 - 1))) << 23)
                         : DAMPING;
        const float two_mu = 2.0f * mu;
        const float mu4sq  = 4.0f * mu * mu;

        v2f s0v = {0.0f, 0.0f}, s2v = {0.0f, 0.0f};
        #pragma unroll
        for (int k = 0; k < NG; ++k) {
            const v2f wk  = w[k];
            const v2f r   = lam * wk + c[k];              // reduced cost
            const v2f a   = __builtin_elementwise_abs(r);
            const v2f D   = r * r + mu4sq;                // exact: (r+2mu)^2-4mu r
            const v2f s   = pk_sqrt(D);
            const v2f den = (a + two_mu) + s;             // > 0, no cancellation
            const v2f rd  = pk_rcp(den);
            const v2f xp  = two_mu * rd;                  // x' in (0, 0.5]
            const v2f cs  = pk_copysign(0.5f - xp, r);
            const v2f xk  = 0.5f - cs;                    // true x in (0,1)
            const v2f A   = 0.5f * den;                   // mu/x'
            const v2f Bq  = A - a;                        // mu/(1-x')
            const v2f AB  = A * A + Bq * Bq;              // H*mu (symmetric)
            const v2f wi  = (mu * wk) * pk_rcp(AB);       // w/H
            s0v = wk * xk + s0v;                          // sum w*x
            s2v = wk * wi + s2v;                          // sum w^2/H
            x[k] = xk; wih[k] = wi;
        }
        float s0 = s0v.x + s0v.y, s2 = s2v.x + s2v.y;
        block_reduce2(s0, s2, ldsR[it & 1]);              // ONE barrier/iter
        dlam = bcast_first((s0 - CAPACITY) * raw_rcp(s2));

        // Scalar-uniform exit: >=2 final-mu Newtons done and |dlam| tiny =>
        // lam within ~1e-5 of lam*; x-error <= w*iH*|dlam| ~ 6e-4; the emit
        // refine absorbs the first-order part. Noise floor of dlam ~ 5e-7.
        if (it >= GATE_IT && fabsf(dlam) < GATE_EPS) break;
        lam += dlam;
    }

    // ---- Emit: out = x - dlam*w/H (the KKT refine; F1==0, s1==0) ----
    float4* o4 = reinterpret_cast<float4*>(out + (size_t)row * N_ELEM);
    #pragma unroll
    for (int j = 0; j < NG / 2; ++j) {
        F4V2 ov;
        #pragma unroll
        for (int h = 0; h < 2; ++h) {
            const int k = 2 * j + h;
            ov.v[h] = x[k] - dlam * wih[k];
        }
        o4[t + BLOCK * j] = ov.f4;
    }
}

extern "C" void kernel_launch(void* const* d_in, const int* in_sizes, int n_in,
                              void* d_out, int out_size, void* d_ws, size_t ws_size,
                              hipStream_t stream) {
    const float* costs   = (const float*)d_in[0];
    const float* weights = (const float*)d_in[1];
    float* out = (float*)d_out;
    const int B = in_sizes[0] / N_ELEM;   // 2048 rows
    ipm_knapsack_kernel<<<B, BLOCK, 0, stream>>>(costs, weights, out);
}